// Round 4
// baseline (472.907 us; speedup 1.0000x reference)
//
#include <hip/hip_runtime.h>
#include <hip/hip_bf16.h>

#define NN 8192
#define DIM 128
#define BM 32
#define BK 64
#define NT (NN / BK)

typedef __attribute__((ext_vector_type(4))) float f32x4;
typedef __attribute__((ext_vector_type(8))) short bf16x8;
typedef __attribute__((ext_vector_type(4))) short bf16x4;

static __device__ __forceinline__ short f2bf(float f) {
    __hip_bfloat16 h = __float2bfloat16(f);
    return *reinterpret_cast<short*>(&h);
}
static __device__ __forceinline__ float bf2f(short s) {
    union { unsigned int u; float f; } c;
    c.u = ((unsigned int)(unsigned short)s) << 16;
    return c.f;
}

// ---------------- kernel 1: degree row-sums -> d^{-1/2} ----------------
__global__ __launch_bounds__(256) void k_rowsum(const float* __restrict__ A,
                                                float* __restrict__ dinv) {
    const int row = blockIdx.x;
    const int t = threadIdx.x;
    const float4* a4 = reinterpret_cast<const float4*>(A + (size_t)row * NN);
    float s = 0.f;
#pragma unroll
    for (int q = 0; q < 8; ++q) {
        float4 v = a4[q * 256 + t];
        s += (v.x + v.y) + (v.z + v.w);
    }
#pragma unroll
    for (int off = 32; off > 0; off >>= 1) s += __shfl_down(s, off);
    __shared__ float red[4];
    if ((t & 63) == 0) red[t >> 6] = s;
    __syncthreads();
    if (t == 0) {
        float deg = red[0] + red[1] + red[2] + red[3] + 1.0f;   // +I self-loop
        dinv[row] = 1.0f / sqrtf(deg);
    }
}

// ------- kernel 2: Yt[f'][j] = bf16( dinv[j] * sum_f X[j][f] * W[f'][f] ) -------
// grid = (NN/32)*2 blocks; block handles 32 j-rows x 64 f'-columns (half of W).
__global__ __launch_bounds__(256) void k_y(const float* __restrict__ X,
                                           const float* __restrict__ W,
                                           const float* __restrict__ dinv,
                                           short* __restrict__ Yt) {
    __shared__ float Wl[64 * 128];
    __shared__ float Xl[32 * 129];   // +1 pad: conflict-free lane=j reads
    const int t = threadIdx.x;
    const int j0 = (blockIdx.x >> 1) * 32;
    const int half = blockIdx.x & 1;

    const float4* wg = reinterpret_cast<const float4*>(W + (size_t)half * 64 * 128);
#pragma unroll
    for (int q = 0; q < 8; ++q)
        reinterpret_cast<float4*>(Wl)[q * 256 + t] = wg[q * 256 + t];
#pragma unroll
    for (int q = 0; q < 4; ++q) {
        int p = q * 256 + t;
        int row = p >> 5, c4 = p & 31;
        float4 v = reinterpret_cast<const float4*>(X + (size_t)(j0 + row) * DIM)[c4];
        float* dst = Xl + row * 129 + c4 * 4;
        dst[0] = v.x; dst[1] = v.y; dst[2] = v.z; dst[3] = v.w;
    }
    __syncthreads();

    const int j = t & 31;
    const int fb = t >> 5;             // 0..7
    const float dj = dinv[j0 + j];
    float acc[8];
#pragma unroll
    for (int k = 0; k < 8; ++k) acc[k] = 0.f;
    for (int f = 0; f < DIM; ++f) {
        float xv = Xl[j * 129 + f];
#pragma unroll
        for (int k = 0; k < 8; ++k)
            acc[k] = fmaf(xv, Wl[(fb + k * 8) * 128 + f], acc[k]);
    }
#pragma unroll
    for (int k = 0; k < 8; ++k)
        Yt[(size_t)(half * 64 + fb + k * 8) * NN + j0 + j] = f2bf(dj * acc[k]);
}

// ---------------- kernel 3: out = dinv[i]*( (A @ Y)[i,f] + Y[i,f] ) + b[f] ----------------
// grid = NN/BM = 256 blocks, 512 threads = 8 waves (2 M x 4 N), 16x16x32 bf16 MFMA.
__global__ __launch_bounds__(512) void k_main(const float* __restrict__ A,
                                              const short* __restrict__ Yt,
                                              const float* __restrict__ dinv,
                                              const float* __restrict__ bias,
                                              float* __restrict__ out) {
    __shared__ short Ab[2][BM * BK];    // [32][64] bf16, XOR-swizzled rows (128 B)
    __shared__ short Yb[2][DIM * BK];   // [128][64] bf16 (Yt layout: [f][k])

    const int t = threadIdx.x;
    const int i0 = blockIdx.x * BM;

    // ---- staging addresses ----
    const int ar = t >> 4;                 // A row 0..31
    const int ac4 = t & 15;                // float4 col 0..15
    const float4* aG = reinterpret_cast<const float4*>(A + (size_t)(i0 + ar) * NN) + ac4;
    const int aLoff = ar * 128 + ((ac4 * 8) ^ ((ar & 7) << 4));   // bytes

    const int yr0 = t >> 3;                // f rows 0..63
    const int yc0 = t & 7;                 // 16B chunk 0..7
    const int yr1 = yr0 + 64;
    const short* yG0 = Yt + (size_t)yr0 * NN + yc0 * 8;
    const short* yG1 = Yt + (size_t)yr1 * NN + yc0 * 8;
    const int yLoff0 = yr0 * 128 + ((yc0 * 16) ^ ((yr0 & 7) << 4));
    const int yLoff1 = yr1 * 128 + ((yc0 * 16) ^ ((yr1 & 7) << 4));

    // ---- fragment read offsets ----
    const int lane = t & 63;
    const int wid = t >> 6;
    const int wm = wid >> 2, wn = wid & 3;
    const int l15 = lane & 15, lk = lane >> 4;

    int offA[2], offB[2][2];
#pragma unroll
    for (int kc = 0; kc < 2; ++kc) {
        const int bcol = kc * 64 + lk * 16;          // byte col within 128-B row
        const int arow = wm * 16 + l15;
        offA[kc] = arow * 128 + (bcol ^ ((arow & 7) << 4));
#pragma unroll
        for (int fn = 0; fn < 2; ++fn) {
            const int f = wn * 32 + fn * 16 + l15;
            offB[fn][kc] = f * 128 + (bcol ^ ((f & 7) << 4));
        }
    }

    f32x4 acc[2] = {{0.f, 0.f, 0.f, 0.f}, {0.f, 0.f, 0.f, 0.f}};

    // ---- prologue: stage tile 0 ----
    {
        float4 av = aG[0];
        int4 y0 = *reinterpret_cast<const int4*>(yG0);
        int4 y1 = *reinterpret_cast<const int4*>(yG1);
        bf16x4 a16 = { f2bf(av.x), f2bf(av.y), f2bf(av.z), f2bf(av.w) };
        *reinterpret_cast<bf16x4*>(reinterpret_cast<char*>(Ab[0]) + aLoff) = a16;
        *reinterpret_cast<int4*>(reinterpret_cast<char*>(Yb[0]) + yLoff0) = y0;
        *reinterpret_cast<int4*>(reinterpret_cast<char*>(Yb[0]) + yLoff1) = y1;
    }
    __syncthreads();

    for (int kt = 0; kt < NT; ++kt) {
        const int cur = kt & 1;
        const int nxt = (kt < NT - 1) ? kt + 1 : kt;

        // prefetch next tile (global -> regs), hidden under compute
        float4 av = aG[nxt * 16];
        int4 y0 = *reinterpret_cast<const int4*>(yG0 + nxt * BK);
        int4 y1 = *reinterpret_cast<const int4*>(yG1 + nxt * BK);

        // compute current tile
        const char* ab = reinterpret_cast<const char*>(Ab[cur]);
        const char* yb = reinterpret_cast<const char*>(Yb[cur]);
        bf16x8 a0  = *reinterpret_cast<const bf16x8*>(ab + offA[0]);
        bf16x8 a1  = *reinterpret_cast<const bf16x8*>(ab + offA[1]);
        bf16x8 b00 = *reinterpret_cast<const bf16x8*>(yb + offB[0][0]);
        bf16x8 b01 = *reinterpret_cast<const bf16x8*>(yb + offB[0][1]);
        bf16x8 b10 = *reinterpret_cast<const bf16x8*>(yb + offB[1][0]);
        bf16x8 b11 = *reinterpret_cast<const bf16x8*>(yb + offB[1][1]);
        acc[0] = __builtin_amdgcn_mfma_f32_16x16x32_bf16(a0, b00, acc[0], 0, 0, 0);
        acc[0] = __builtin_amdgcn_mfma_f32_16x16x32_bf16(a1, b01, acc[0], 0, 0, 0);
        acc[1] = __builtin_amdgcn_mfma_f32_16x16x32_bf16(a0, b10, acc[1], 0, 0, 0);
        acc[1] = __builtin_amdgcn_mfma_f32_16x16x32_bf16(a1, b11, acc[1], 0, 0, 0);

        // stage next tile into the other buffer
        {
            bf16x4 a16 = { f2bf(av.x), f2bf(av.y), f2bf(av.z), f2bf(av.w) };
            char* abw = reinterpret_cast<char*>(Ab[cur ^ 1]);
            char* ybw = reinterpret_cast<char*>(Yb[cur ^ 1]);
            *reinterpret_cast<bf16x4*>(abw + aLoff) = a16;
            *reinterpret_cast<int4*>(ybw + yLoff0) = y0;
            *reinterpret_cast<int4*>(ybw + yLoff1) = y1;
        }
        __syncthreads();
    }

    // ---- epilogue: out[i][f] = dinv[i]*(acc + Y[i][f]) + b[f] ----
    const int iBase = i0 + wm * 16 + lk * 4;
    const float4 dv4 = *reinterpret_cast<const float4*>(dinv + iBase);
    const float dvr[4] = { dv4.x, dv4.y, dv4.z, dv4.w };
#pragma unroll
    for (int fn = 0; fn < 2; ++fn) {
        const int f = wn * 32 + fn * 16 + l15;
        const float bf_ = bias[f];
        bf16x4 yv = *reinterpret_cast<const bf16x4*>(Yt + (size_t)f * NN + iBase);
#pragma unroll
        for (int r = 0; r < 4; ++r) {
            float z = acc[fn][r] + bf2f(yv[r]);
            out[(size_t)(iBase + r) * DIM + f] = dvr[r] * z + bf_;
        }
    }
}

extern "C" void kernel_launch(void* const* d_in, const int* in_sizes, int n_in,
                              void* d_out, int out_size, void* d_ws, size_t ws_size,
                              hipStream_t stream) {
    (void)in_sizes; (void)n_in; (void)out_size; (void)ws_size;
    const float* X = (const float*)d_in[0];
    const float* A = (const float*)d_in[1];
    const float* W = (const float*)d_in[2];
    const float* b = (const float*)d_in[3];
    float* out = (float*)d_out;

    float* dinv = (float*)d_ws;                                  // 8192 f32
    short* Yt = (short*)((char*)d_ws + NN * sizeof(float));      // [128][8192] bf16

    k_rowsum<<<NN, 256, 0, stream>>>(A, dinv);
    k_y<<<(NN / 32) * 2, 256, 0, stream>>>(X, W, dinv, Yt);
    k_main<<<NN / BM, 512, 0, stream>>>(A, Yt, dinv, b, out);
}